// Round 5
// baseline (345.166 us; speedup 1.0000x reference)
//
#include <hip/hip_runtime.h>
#include <hip/hip_bf16.h>
#include <cstdint>
#include <cstddef>

// TT-dense: y = relu(x @ M + b)
// x: [4096,4096] f32, M: TT(cores r=1,16,16,16,1, dims 8^4 x 8^4), out f32.
//
// Route: materialize M^T in bf16 (~0.67 GFLOP), convert x to bf16, one
// 4096^3 bf16 MFMA GEMM with fused bias+relu.
// R2: swizzle killed bank conflicts at BK=32 (1.7e7 -> 0), 190us GEMM.
// R3: ping-pong dbuf REGRESSED (dynamic LDS indexing -> VALU bound); reverted.
// R4: BK=64 m97-replica: 165us GEMM, but conflicts returned (1.678e7 ==
//     2.10M ds_read_b128 x 8 cyc: with 128B row stride, bank group depends
//     only on chunk position; half-rate rotation covered 4/8 positions).
// R5: full-rate rotation p=(h+r)&7 (exact inverse at stage time); fuse all
//     pre-GEMM work into ONE dispatch (Mt blocks self-compute their 2KB of
//     G-slices -> no cross-kernel dep); XCD-aware 8x16 block tiling.

#define GM 4096
#define GN 4096
#define GK 4096

#define MT_BLOCKS 4096
#define CONV_BLOCKS 8192  // (4096*4096)/(256*8)

typedef __attribute__((ext_vector_type(8))) short short8_t;
typedef __attribute__((ext_vector_type(4))) float float4_t;

__device__ __forceinline__ unsigned short f2bf(float f) {
  union { float f; uint32_t u; } v; v.f = f;
  uint32_t u = v.u;
  uint32_t r = (u + 0x7fffu + ((u >> 16) & 1u)) >> 16;  // RNE
  return (unsigned short)r;
}

// ---------------------------------------------------------------------------
// Kernel 1 (fully fused pre-GEMM):
//  blocks [0, MT_BLOCKS): block n computes Mt row n (n = b01*64 + b23).
//    Phase A: G01s[r2][a01] = sum_r1 c0[a0,b0,r1]*c1[r1,a1,b1,r2]  (b01 fixed)
//             G23s[r2][a23] = sum_r3 c2[r2,a2,b2,r3]*c3[r3,a3,b3]  (b23 fixed)
//    Phase B: Mt[n][k] = sum_r2 G01s[r2][k>>6] * G23s[r2][k&63], bf16 store.
//  blocks [MT_BLOCKS, MT_BLOCKS+CONV_BLOCKS): x f32 -> bf16 (8 elem/thread).
// ---------------------------------------------------------------------------
__global__ __launch_bounds__(256) void pre_kernel(
    const float* __restrict__ c0, const float* __restrict__ c1,
    const float* __restrict__ c2, const float* __restrict__ c3,
    const float* __restrict__ x, unsigned short* __restrict__ xb,
    unsigned short* __restrict__ Mt) {
  int bid = blockIdx.x;
  if (bid < MT_BLOCKS) {
    __shared__ float G01s[16 * 64];  // [r2][a01] (transposed: broadcast reads)
    __shared__ float G23s[16 * 64];  // [r2][a23]
    int b01 = bid >> 6, b23 = bid & 63;
    int b0 = b01 >> 3, b1 = b01 & 7, b2 = b23 >> 3, b3 = b23 & 7;
    int tid = threadIdx.x;
#pragma unroll
    for (int u = 0; u < 4; ++u) {
      int e = tid * 4 + u;  // 0..1023
      {
        int a01 = e >> 4, r2 = e & 15;
        int a0 = a01 >> 3, a1 = a01 & 7;
        float s = 0.f;
#pragma unroll
        for (int r1 = 0; r1 < 16; ++r1)
          s += c0[(a0 * 8 + b0) * 16 + r1] *
               c1[((r1 * 8 + a1) * 8 + b1) * 16 + r2];
        G01s[r2 * 64 + a01] = s;
      }
      {
        int r2 = e >> 6, a23 = e & 63;
        int a2 = a23 >> 3, a3 = a23 & 7;
        float s = 0.f;
#pragma unroll
        for (int r3 = 0; r3 < 16; ++r3)
          s += c2[((r2 * 8 + a2) * 8 + b2) * 16 + r3] *
               c3[(r3 * 8 + a3) * 8 + b3];
        G23s[r2 * 64 + a23] = s;
      }
    }
    __syncthreads();

    // Phase B: thread covers k = tid*16 .. +15 -> a01 = tid>>2 (fixed),
    // a23 = (tid&3)*16 + i.
    int a01 = tid >> 2;
    int a23b = (tid & 3) * 16;
    float acc[16];
#pragma unroll
    for (int i = 0; i < 16; ++i) acc[i] = 0.f;
    for (int r2 = 0; r2 < 16; ++r2) {
      float g = G01s[r2 * 64 + a01];  // 4-lane broadcast, conflict-free
      const float* row = &G23s[r2 * 64 + a23b];
      float4_t v0 = *(const float4_t*)(row);
      float4_t v1 = *(const float4_t*)(row + 4);
      float4_t v2 = *(const float4_t*)(row + 8);
      float4_t v3 = *(const float4_t*)(row + 12);
#pragma unroll
      for (int l = 0; l < 4; ++l) {
        acc[l]      += g * v0[l];
        acc[4 + l]  += g * v1[l];
        acc[8 + l]  += g * v2[l];
        acc[12 + l] += g * v3[l];
      }
    }
    short8_t o0, o1;
#pragma unroll
    for (int i = 0; i < 8; ++i) {
      o0[i] = (short)f2bf(acc[i]);
      o1[i] = (short)f2bf(acc[8 + i]);
    }
    size_t base = (size_t)bid * GK + tid * 16;
    *(short8_t*)(Mt + base) = o0;
    *(short8_t*)(Mt + base + 8) = o1;
  } else {
    int i = ((bid - MT_BLOCKS) * 256 + threadIdx.x) * 8;
    float4_t a = *(const float4_t*)(x + i);
    float4_t b = *(const float4_t*)(x + i + 4);
    short8_t o;
    o[0] = (short)f2bf(a[0]); o[1] = (short)f2bf(a[1]);
    o[2] = (short)f2bf(a[2]); o[3] = (short)f2bf(a[3]);
    o[4] = (short)f2bf(b[0]); o[5] = (short)f2bf(b[1]);
    o[6] = (short)f2bf(b[2]); o[7] = (short)f2bf(b[3]);
    *(short8_t*)(xb + i) = o;
  }
}

// ---------------------------------------------------------------------------
// Kernel 2: C = relu(A @ Bt^T + bias). A:[M][K] bf16, Bt:[N][K] bf16.
// 128x128 tile, BK=64 (32 KB LDS), 4 waves (2x2), global_load_lds width-16
// staging, 16x16x32 bf16 MFMA, single buffer, 2 barriers / 32 MFMA per iter.
//
// LDS chunk swizzle (full-rate): row r (64 bf16 = 8 x 16B chunks) stores
// k-half h at position p = (h + r) & 7. With 128B row stride the bank group
// depends only on p, so 8 consecutive rows at fixed h cover all 8 positions
// -> all 32 banks, 0 conflicts. Staging keeps the lane-contiguous LDS dest
// required by global_load_lds and permutes the global source k-offset:
// chunk c (row r=c>>3, pos p=c&7) fetches h = (p - r) & 7; the 8 lanes of a
// row still cover the full 128B row (permuted) -> fully coalesced.
//
// XCD swizzle: all 1024 blocks co-resident (4/CU); give each XCD an 8x16
// tile of the 32x32 block grid (streams 24 panels/XCD instead of 36).
// ---------------------------------------------------------------------------
__global__ __launch_bounds__(256) void gemm_bias_relu(
    const unsigned short* __restrict__ A, const unsigned short* __restrict__ Bt,
    const float* __restrict__ bias, float* __restrict__ C) {
  __shared__ __align__(16) unsigned short As[128 * 64];  // 16 KB
  __shared__ __align__(16) unsigned short Bs[128 * 64];  // 16 KB

  int tid = threadIdx.x;
  int bswz = blockIdx.x;
  int xcd = bswz & 7, li = bswz >> 3;
  int row0 = (((xcd >> 1) * 8) + (li >> 4)) * 128;   // 32 row-blocks
  int col0 = (((xcd & 1) * 16) + (li & 15)) * 128;   // 32 col-blocks
  int wave = tid >> 6, lane = tid & 63;
  int wr = (wave >> 1) * 64, wc = (wave & 1) * 64;
  int half = lane >> 4, mrow = lane & 15;

  float4_t acc[4][4];
#pragma unroll
  for (int i = 0; i < 4; ++i)
#pragma unroll
    for (int j = 0; j < 4; ++j) acc[i][j] = (float4_t){0.f, 0.f, 0.f, 0.f};

  // Staging: thread owns chunks c = q*256+tid (q=0..3) per matrix.
  // Chunk c: row r = c>>3, pos p = c&7, source k-half h = (p - r) & 7.
  const unsigned short* Ap[4];
  const unsigned short* Bp[4];
  int cdst[4];
#pragma unroll
  for (int q = 0; q < 4; ++q) {
    int c = q * 256 + tid;
    int r = c >> 3;
    int h = ((c & 7) - r) & 7;
    Ap[q] = A + (size_t)(row0 + r) * GK + h * 8;
    Bp[q] = Bt + (size_t)(col0 + r) * GK + h * 8;
    cdst[q] = c * 8;  // shorts
  }

  // Swizzled fragment offsets (loop-invariant): k-step ks in {0,1};
  // wanted k-half hw = ks*4 + half, read position p = (hw + r) & 7.
  int aoff[2][4], boff[2][4];
#pragma unroll
  for (int ks = 0; ks < 2; ++ks) {
#pragma unroll
    for (int i = 0; i < 4; ++i) {
      int rA = wr + i * 16 + mrow;
      aoff[ks][i] = rA * 64 + ((((ks * 4 + half) + rA) & 7) * 8);
      int rB = wc + i * 16 + mrow;
      boff[ks][i] = rB * 64 + ((((ks * 4 + half) + rB) & 7) * 8);
    }
  }

  for (int k0 = 0; k0 < GK; k0 += 64) {
#pragma unroll
    for (int q = 0; q < 4; ++q) {
      __builtin_amdgcn_global_load_lds(
          (const __attribute__((address_space(1))) void*)(Ap[q] + k0),
          (__attribute__((address_space(3))) void*)(As + cdst[q]), 16, 0, 0);
      __builtin_amdgcn_global_load_lds(
          (const __attribute__((address_space(1))) void*)(Bp[q] + k0),
          (__attribute__((address_space(3))) void*)(Bs + cdst[q]), 16, 0, 0);
    }
    __syncthreads();

#pragma unroll
    for (int ks = 0; ks < 2; ++ks) {
      short8_t af[4], bfr[4];
#pragma unroll
      for (int i = 0; i < 4; ++i) af[i] = *(const short8_t*)&As[aoff[ks][i]];
#pragma unroll
      for (int j = 0; j < 4; ++j) bfr[j] = *(const short8_t*)&Bs[boff[ks][j]];
#pragma unroll
      for (int i = 0; i < 4; ++i)
#pragma unroll
        for (int j = 0; j < 4; ++j)
          acc[i][j] = __builtin_amdgcn_mfma_f32_16x16x32_bf16(af[i], bfr[j],
                                                              acc[i][j], 0, 0, 0);
    }
    __syncthreads();
  }

  // Epilogue: C/D layout col=lane&15, row=(lane>>4)*4+reg. Fuse bias+relu.
#pragma unroll
  for (int j = 0; j < 4; ++j) {
    int col = col0 + wc + j * 16 + mrow;
    float bcol = bias[col];
#pragma unroll
    for (int i = 0; i < 4; ++i) {
#pragma unroll
      for (int r = 0; r < 4; ++r) {
        int row = row0 + wr + i * 16 + half * 4 + r;
        float v = acc[i][j][r] + bcol;
        C[(size_t)row * GN + col] = v > 0.f ? v : 0.f;
      }
    }
  }
}

// ---------------------------------------------------------------------------
extern "C" void kernel_launch(void* const* d_in, const int* in_sizes, int n_in,
                              void* d_out, int out_size, void* d_ws, size_t ws_size,
                              hipStream_t stream) {
  const float* x  = (const float*)d_in[0];
  const float* c0 = (const float*)d_in[1];
  const float* c1 = (const float*)d_in[2];
  const float* c2 = (const float*)d_in[3];
  const float* c3 = (const float*)d_in[4];
  const float* b  = (const float*)d_in[5];
  float* out = (float*)d_out;

  // Workspace layout: [xb 32MB][Mt 32MB]
  unsigned short* xb = (unsigned short*)d_ws;
  unsigned short* Mt = (unsigned short*)((char*)d_ws + (32u << 20));

  pre_kernel<<<MT_BLOCKS + CONV_BLOCKS, 256, 0, stream>>>(
      c0, c1, c2, c3, x, xb, Mt);
  gemm_bias_relu<<<(GM / 128) * (GN / 128), 256, 0, stream>>>(xb, Mt, b, out);
}